// Round 1
// baseline (324.463 us; speedup 1.0000x reference)
//
#include <hip/hip_runtime.h>
#include <hip/hip_bf16.h>

// Problem constants
#define B_   8
#define S_   1024
#define D_   768
#define H_   16
#define PD_  48
#define PDP  64        // padded per-head dim
#define M_   8192      // B*S
#define BH_  128       // B*H

typedef __attribute__((ext_vector_type(8))) short short8;
typedef __attribute__((ext_vector_type(4))) float floatx4;

__device__ __forceinline__ unsigned short f2bf(float f) {
    __hip_bfloat16 h = __float2bfloat16(f);
    return *reinterpret_cast<unsigned short*>(&h);
}

// ---------------------------------------------------------------- convert X
__global__ __launch_bounds__(256) void convert_x_kernel(
    const float* __restrict__ X, unsigned short* __restrict__ Xb) {
    long i = ((long)blockIdx.x * 256 + threadIdx.x) * 4;
    float4 v = *(const float4*)(X + i);
    ushort4 o;
    o.x = f2bf(v.x); o.y = f2bf(v.y); o.z = f2bf(v.z); o.w = f2bf(v.w);
    *(ushort4*)(Xb + i) = o;
}

// ------------------------------------------------- transpose + cast weights
// Wt[n][k] = bf16(W[k][n]); z selects which of the 4 weight matrices.
__global__ __launch_bounds__(256) void transpose_w_kernel(
    const float* __restrict__ w0, const float* __restrict__ w1,
    const float* __restrict__ w2, const float* __restrict__ w3,
    unsigned short* __restrict__ Wtall) {
    __shared__ float tile[32][33];
    const int tx = threadIdx.x, ty = threadIdx.y;
    const int nt = blockIdx.x * 32, kt = blockIdx.y * 32, z = blockIdx.z;
    const float* W = (z == 0) ? w0 : (z == 1) ? w1 : (z == 2) ? w2 : w3;
    unsigned short* Wt = Wtall + (long)z * D_ * D_;
#pragma unroll
    for (int i = 0; i < 4; i++)
        tile[ty + i * 8][tx] = W[(long)(kt + ty + i * 8) * D_ + nt + tx];
    __syncthreads();
#pragma unroll
    for (int i = 0; i < 4; i++)
        Wt[(long)(nt + ty + i * 8) * D_ + kt + tx] = f2bf(tile[tx][ty + i * 8]);
}

// --------------------------------------------------------------- GEMM core
// C[128x128] = A[128xK] * Bt[128xK]^T, bf16 in, fp32 acc.
// LDS XOR-swizzle: element (row, k) stored at row*64 + ((k>>3)^(row&7))*8 + (k&7)
__device__ __forceinline__ void gemm_core(
    const unsigned short* __restrict__ Ag,   // A rows at m0, stride D_
    const unsigned short* __restrict__ Btg,  // Bt rows at n0, stride D_
    unsigned short* Asm, unsigned short* Bsm, floatx4 acc[4][4]) {
    const int tid = threadIdx.x;
    const int lane = tid & 63, w = tid >> 6;
    const int wr = (w >> 1) * 64, wc = (w & 1) * 64;
    const int l15 = lane & 15, l4 = lane >> 4;
    const floatx4 zero = {0.f, 0.f, 0.f, 0.f};
#pragma unroll
    for (int mt = 0; mt < 4; mt++)
#pragma unroll
        for (int nt = 0; nt < 4; nt++) acc[mt][nt] = zero;

    for (int kb = 0; kb < D_; kb += 64) {
#pragma unroll
        for (int i = 0; i < 4; i++) {
            int s5 = tid + i * 256;
            int row = s5 >> 3, seg = s5 & 7;
            int ps = (seg ^ (row & 7)) * 8;
            *(uint4*)&Asm[row * 64 + ps] = *(const uint4*)&Ag[(long)row * D_ + kb + seg * 8];
            *(uint4*)&Bsm[row * 64 + ps] = *(const uint4*)&Btg[(long)row * D_ + kb + seg * 8];
        }
        __syncthreads();
#pragma unroll
        for (int kk = 0; kk < 2; kk++) {
            short8 af[4], bf[4];
#pragma unroll
            for (int mt = 0; mt < 4; mt++) {
                int r = wr + mt * 16 + l15;
                af[mt] = *(const short8*)&Asm[r * 64 + ((kk * 4 + l4) ^ (r & 7)) * 8];
            }
#pragma unroll
            for (int nt = 0; nt < 4; nt++) {
                int c = wc + nt * 16 + l15;
                bf[nt] = *(const short8*)&Bsm[c * 64 + ((kk * 4 + l4) ^ (c & 7)) * 8];
            }
#pragma unroll
            for (int mt = 0; mt < 4; mt++)
#pragma unroll
                for (int nt = 0; nt < 4; nt++)
                    acc[mt][nt] = __builtin_amdgcn_mfma_f32_16x16x32_bf16(
                        af[mt], bf[nt], acc[mt][nt], 0, 0, 0);
        }
        __syncthreads();
    }
}

// ------------------------------------------------------- QKV projection GEMM
// z = 0/1/2 -> Q/K/V. Output layout [b,h,s,PDP] bf16 (d padded; pads pre-zeroed).
__global__ __launch_bounds__(256) void gemm_qkv_kernel(
    const unsigned short* __restrict__ Xb, const unsigned short* __restrict__ Wtall,
    const float* __restrict__ bq, const float* __restrict__ bk,
    const float* __restrict__ bv, unsigned short* __restrict__ QKV) {
    __shared__ __align__(16) unsigned short Asm[128 * 64];
    __shared__ __align__(16) unsigned short Bsm[128 * 64];
    const int z = blockIdx.z;
    const int m0 = blockIdx.y * 128, n0 = blockIdx.x * 128;
    const float* bias = (z == 0) ? bq : (z == 1) ? bk : bv;
    floatx4 acc[4][4];
    gemm_core(Xb + (long)m0 * D_, Wtall + (long)z * D_ * D_ + (long)n0 * D_, Asm, Bsm, acc);

    unsigned short* out = QKV + (long)z * BH_ * S_ * PDP;
    const int tid = threadIdx.x, lane = tid & 63, w = tid >> 6;
    const int wr = (w >> 1) * 64, wc = (w & 1) * 64;
    const int l15 = lane & 15, l4 = lane >> 4;
#pragma unroll
    for (int nt = 0; nt < 4; nt++) {
        int n = n0 + wc + nt * 16 + l15;
        int h = n / PD_, pd = n % PD_;
        float bb = bias[n];
#pragma unroll
        for (int mt = 0; mt < 4; mt++) {
#pragma unroll
            for (int r = 0; r < 4; r++) {
                int m = m0 + wr + mt * 16 + l4 * 4 + r;
                int b = m >> 10, s = m & 1023;
                out[((long)(b * H_ + h) * S_ + s) * PDP + pd] = f2bf(acc[mt][nt][r] + bb);
            }
        }
    }
}

// --------------------------------------------------------- output projection
__global__ __launch_bounds__(256) void gemm_out_kernel(
    const unsigned short* __restrict__ Ctx, const unsigned short* __restrict__ Wot,
    const float* __restrict__ bo, float* __restrict__ Out) {
    __shared__ __align__(16) unsigned short Asm[128 * 64];
    __shared__ __align__(16) unsigned short Bsm[128 * 64];
    const int m0 = blockIdx.y * 128, n0 = blockIdx.x * 128;
    floatx4 acc[4][4];
    gemm_core(Ctx + (long)m0 * D_, Wot + (long)n0 * D_, Asm, Bsm, acc);

    const int tid = threadIdx.x, lane = tid & 63, w = tid >> 6;
    const int wr = (w >> 1) * 64, wc = (w & 1) * 64;
    const int l15 = lane & 15, l4 = lane >> 4;
#pragma unroll
    for (int nt = 0; nt < 4; nt++) {
        int n = n0 + wc + nt * 16 + l15;
        float bb = bo[n];
#pragma unroll
        for (int mt = 0; mt < 4; mt++) {
#pragma unroll
            for (int r = 0; r < 4; r++) {
                int m = m0 + wr + mt * 16 + l4 * 4 + r;
                Out[(long)m * D_ + n] = acc[mt][nt][r] + bb;
            }
        }
    }
}

// ------------------------------------------------------------ flash attention
// One block = (b,h) x 64-query tile; 4 waves x 16 queries each.
__global__ __launch_bounds__(256) void attn_kernel(
    const unsigned short* __restrict__ Qg, const unsigned short* __restrict__ Kg,
    const unsigned short* __restrict__ Vg, unsigned short* __restrict__ Ctx) {
    __shared__ __align__(16) unsigned short Qs[64 * 64];
    __shared__ __align__(16) unsigned short Ks[64 * 64];
    __shared__ __align__(16) unsigned short Vts[64 * 64];  // transposed: [d][key]
    __shared__ __align__(16) unsigned short Ps[4][16 * 64];
    const int tid = threadIdx.x, lane = tid & 63, w = tid >> 6;
    const int l15 = lane & 15, l4 = lane >> 4;
    const int qt = blockIdx.x, bh = blockIdx.y;
    const long base = (long)bh * S_ * PDP;
    const float scale = 0.14433756729740643f;  // 1/sqrt(48)

    // stage Q tile
#pragma unroll
    for (int i = 0; i < 2; i++) {
        int s5 = tid + i * 256;
        int row = s5 >> 3, seg = s5 & 7;
        *(uint4*)&Qs[row * 64 + ((seg ^ (row & 7)) * 8)] =
            *(const uint4*)&Qg[base + (long)(qt * 64 + row) * PDP + seg * 8];
    }
    __syncthreads();
    short8 aq[2];
    {
        int qr = w * 16 + l15;
        aq[0] = *(const short8*)&Qs[qr * 64 + ((0 + l4) ^ (qr & 7)) * 8];
        aq[1] = *(const short8*)&Qs[qr * 64 + ((4 + l4) ^ (qr & 7)) * 8];
    }

    const floatx4 zero = {0.f, 0.f, 0.f, 0.f};
    floatx4 accO[4];
#pragma unroll
    for (int nt = 0; nt < 4; nt++) accO[nt] = zero;
    float mR[4] = {-1e30f, -1e30f, -1e30f, -1e30f};
    float lR[4] = {0.f, 0.f, 0.f, 0.f};

    for (int kt = 0; kt < 16; kt++) {
        __syncthreads();
        // stage K tile
#pragma unroll
        for (int i = 0; i < 2; i++) {
            int s5 = tid + i * 256;
            int row = s5 >> 3, seg = s5 & 7;
            *(uint4*)&Ks[row * 64 + ((seg ^ (row & 7)) * 8)] =
                *(const uint4*)&Kg[base + (long)(kt * 64 + row) * PDP + seg * 8];
        }
        // stage V tile transposed
#pragma unroll
        for (int i = 0; i < 2; i++) {
            int s5 = tid + i * 256;
            int key = s5 >> 3, dseg = s5 & 7;
            uint4 vv = *(const uint4*)&Vg[base + (long)(kt * 64 + key) * PDP + dseg * 8];
            const unsigned short* pv = (const unsigned short*)&vv;
#pragma unroll
            for (int j = 0; j < 8; j++) {
                int d = dseg * 8 + j;
                Vts[d * 64 + (((key >> 3) ^ (d & 7)) * 8) + (key & 7)] = pv[j];
            }
        }
        __syncthreads();

        // scores: Q Kt  (16q x 64k per wave)
        floatx4 sc[4];
#pragma unroll
        for (int ks = 0; ks < 4; ks++) {
            floatx4 a = zero;
            int kr = ks * 16 + l15;
            short8 b0 = *(const short8*)&Ks[kr * 64 + ((0 + l4) ^ (kr & 7)) * 8];
            short8 b1 = *(const short8*)&Ks[kr * 64 + ((4 + l4) ^ (kr & 7)) * 8];
            a = __builtin_amdgcn_mfma_f32_16x16x32_bf16(aq[0], b0, a, 0, 0, 0);
            a = __builtin_amdgcn_mfma_f32_16x16x32_bf16(aq[1], b1, a, 0, 0, 0);
            sc[ks] = a * scale;
        }

        // online softmax (rows = (l4*4+r), cols across l15 x ks)
#pragma unroll
        for (int r = 0; r < 4; r++) {
            float mx = fmaxf(fmaxf(sc[0][r], sc[1][r]), fmaxf(sc[2][r], sc[3][r]));
            mx = fmaxf(mx, __shfl_xor(mx, 1));
            mx = fmaxf(mx, __shfl_xor(mx, 2));
            mx = fmaxf(mx, __shfl_xor(mx, 4));
            mx = fmaxf(mx, __shfl_xor(mx, 8));
            float mn = fmaxf(mR[r], mx);
            float al = __expf(mR[r] - mn);
            float rs = 0.f;
#pragma unroll
            for (int ks = 0; ks < 4; ks++) {
                float p = __expf(sc[ks][r] - mn);
                sc[ks][r] = p;
                rs += p;
            }
            rs += __shfl_xor(rs, 1);
            rs += __shfl_xor(rs, 2);
            rs += __shfl_xor(rs, 4);
            rs += __shfl_xor(rs, 8);
            lR[r] = lR[r] * al + rs;
            mR[r] = mn;
#pragma unroll
            for (int nt = 0; nt < 4; nt++) accO[nt][r] *= al;
        }

        // P -> LDS (wave-private) in A-operand layout source
        unsigned short* Pw = &Ps[w][0];
#pragma unroll
        for (int ks = 0; ks < 4; ks++) {
            int key = ks * 16 + l15;
            int kseg = key >> 3, ko = key & 7;
#pragma unroll
            for (int r = 0; r < 4; r++) {
                int row = l4 * 4 + r;
                Pw[row * 64 + ((kseg ^ (row & 7)) * 8) + ko] = f2bf(sc[ks][r]);
            }
        }

        // PV
#pragma unroll
        for (int kk = 0; kk < 2; kk++) {
            short8 ap = *(const short8*)&Pw[l15 * 64 + ((kk * 4 + l4) ^ (l15 & 7)) * 8];
#pragma unroll
            for (int nt = 0; nt < 4; nt++) {
                int d = nt * 16 + l15;
                short8 bv8 = *(const short8*)&Vts[d * 64 + ((kk * 4 + l4) ^ (d & 7)) * 8];
                accO[nt] = __builtin_amdgcn_mfma_f32_16x16x32_bf16(ap, bv8, accO[nt], 0, 0, 0);
            }
        }
    }

    // epilogue: O / l  -> ctx[b,s,h,pd] bf16 (drop padded nt=3)
    const int b = bh >> 4, h = bh & 15;
#pragma unroll
    for (int r = 0; r < 4; r++) {
        float inv = 1.0f / lR[r];
        int s = qt * 64 + w * 16 + l4 * 4 + r;
        long rowoff = (long)(b * S_ + s) * D_ + h * PD_;
#pragma unroll
        for (int nt = 0; nt < 3; nt++) {
            int dd = nt * 16 + l15;
            Ctx[rowoff + dd] = f2bf(accO[nt][r] * inv);
        }
    }
}

// ---------------------------------------------------------------------------
extern "C" void kernel_launch(void* const* d_in, const int* in_sizes, int n_in,
                              void* d_out, int out_size, void* d_ws, size_t ws_size,
                              hipStream_t stream) {
    const float* X  = (const float*)d_in[0];
    const float* Wq = (const float*)d_in[1];
    const float* bq = (const float*)d_in[2];
    const float* Wk = (const float*)d_in[3];
    const float* bk = (const float*)d_in[4];
    const float* Wv = (const float*)d_in[5];
    const float* bv = (const float*)d_in[6];
    const float* Wo = (const float*)d_in[7];
    const float* bo = (const float*)d_in[8];

    unsigned char* ws = (unsigned char*)d_ws;
    const long XB_BYTES = (long)M_ * D_ * 2;        // 12,582,912
    const long WT_BYTES = (long)D_ * D_ * 2;        // 1,179,648
    const long QKV_BYTES = (long)BH_ * S_ * PDP * 2;  // 16,777,216

    unsigned short* Xbf   = (unsigned short*)(ws);
    unsigned short* Wtall = (unsigned short*)(ws + XB_BYTES);
    unsigned short* Qws   = (unsigned short*)(ws + XB_BYTES + 4 * WT_BYTES);
    unsigned short* Kws   = Qws + QKV_BYTES / 2;
    unsigned short* Vws   = Kws + QKV_BYTES / 2;
    unsigned short* Ctx   = Vws + QKV_BYTES / 2;

    // zero Q and K pads (d=48..63 never written by GEMM; must be 0 for QK^T)
    hipMemsetAsync(Qws, 0, 2 * QKV_BYTES, stream);

    convert_x_kernel<<<(M_ * D_) / (256 * 4), 256, 0, stream>>>(X, Xbf);
    transpose_w_kernel<<<dim3(24, 24, 4), dim3(32, 8), 0, stream>>>(Wq, Wk, Wv, Wo, Wtall);
    gemm_qkv_kernel<<<dim3(6, 64, 3), 256, 0, stream>>>(Xbf, Wtall, bq, bk, bv, Qws);
    attn_kernel<<<dim3(16, 128), 256, 0, stream>>>(Qws, Kws, Vws, Ctx);
    gemm_out_kernel<<<dim3(6, 64), 256, 0, stream>>>(
        Ctx, Wtall + 3 * (WT_BYTES / 2), bo, (float*)d_out);
}

// Round 2
// 249.292 us; speedup vs baseline: 1.3015x; 1.3015x over previous
//
#include <hip/hip_runtime.h>
#include <hip/hip_bf16.h>

// Problem constants
#define B_   8
#define S_   1024
#define D_   768
#define H_   16
#define PD_  48
#define PDP  64        // padded per-head dim
#define M_   8192      // B*S
#define BH_  128       // B*H

// 1/sqrt(48) * log2(e)  -> folded into Q so softmax is a bare v_exp (exp2)
#define QSCALE 0.20823031f

typedef __attribute__((ext_vector_type(8))) short short8;
typedef __attribute__((ext_vector_type(4))) float floatx4;

__device__ __forceinline__ unsigned short f2bf(float f) {
    __hip_bfloat16 h = __float2bfloat16(f);
    return *reinterpret_cast<unsigned short*>(&h);
}

// ---------------------------------------------------------------- convert X
__global__ __launch_bounds__(256) void convert_x_kernel(
    const float* __restrict__ X, unsigned short* __restrict__ Xb) {
    long i = ((long)blockIdx.x * 256 + threadIdx.x) * 4;
    float4 v = *(const float4*)(X + i);
    ushort4 o;
    o.x = f2bf(v.x); o.y = f2bf(v.y); o.z = f2bf(v.z); o.w = f2bf(v.w);
    *(ushort4*)(Xb + i) = o;
}

// ------------------------------------------------- transpose + cast weights
__global__ __launch_bounds__(256) void transpose_w_kernel(
    const float* __restrict__ w0, const float* __restrict__ w1,
    const float* __restrict__ w2, const float* __restrict__ w3,
    unsigned short* __restrict__ Wtall) {
    __shared__ float tile[32][33];
    const int tx = threadIdx.x, ty = threadIdx.y;
    const int nt = blockIdx.x * 32, kt = blockIdx.y * 32, z = blockIdx.z;
    const float* W = (z == 0) ? w0 : (z == 1) ? w1 : (z == 2) ? w2 : w3;
    unsigned short* Wt = Wtall + (long)z * D_ * D_;
#pragma unroll
    for (int i = 0; i < 4; i++)
        tile[ty + i * 8][tx] = W[(long)(kt + ty + i * 8) * D_ + nt + tx];
    __syncthreads();
#pragma unroll
    for (int i = 0; i < 4; i++)
        Wt[(long)(nt + ty + i * 8) * D_ + kt + tx] = f2bf(tile[tx][ty + i * 8]);
}

// --------------------------------------------------------------- GEMM core
// C[128x128] = A[128xK] * Bt[128xK]^T, bf16 in, fp32 acc.
// LDS XOR-swizzle: element (row, k) stored at row*64 + ((k>>3)^(row&7))*8 + (k&7)
__device__ __forceinline__ void gemm_core(
    const unsigned short* __restrict__ Ag,   // A rows at m0, stride D_
    const unsigned short* __restrict__ Btg,  // Bt rows at n0, stride D_
    unsigned short* Asm, unsigned short* Bsm, floatx4 acc[4][4]) {
    const int tid = threadIdx.x;
    const int lane = tid & 63, w = tid >> 6;
    const int wr = (w >> 1) * 64, wc = (w & 1) * 64;
    const int l15 = lane & 15, l4 = lane >> 4;
    const floatx4 zero = {0.f, 0.f, 0.f, 0.f};
#pragma unroll
    for (int mt = 0; mt < 4; mt++)
#pragma unroll
        for (int nt = 0; nt < 4; nt++) acc[mt][nt] = zero;

    for (int kb = 0; kb < D_; kb += 64) {
#pragma unroll
        for (int i = 0; i < 4; i++) {
            int s5 = tid + i * 256;
            int row = s5 >> 3, seg = s5 & 7;
            int ps = (seg ^ (row & 7)) * 8;
            *(uint4*)&Asm[row * 64 + ps] = *(const uint4*)&Ag[(long)row * D_ + kb + seg * 8];
            *(uint4*)&Bsm[row * 64 + ps] = *(const uint4*)&Btg[(long)row * D_ + kb + seg * 8];
        }
        __syncthreads();
#pragma unroll
        for (int kk = 0; kk < 2; kk++) {
            short8 af[4], bf[4];
#pragma unroll
            for (int mt = 0; mt < 4; mt++) {
                int r = wr + mt * 16 + l15;
                af[mt] = *(const short8*)&Asm[r * 64 + ((kk * 4 + l4) ^ (r & 7)) * 8];
            }
#pragma unroll
            for (int nt = 0; nt < 4; nt++) {
                int c = wc + nt * 16 + l15;
                bf[nt] = *(const short8*)&Bsm[c * 64 + ((kk * 4 + l4) ^ (c & 7)) * 8];
            }
#pragma unroll
            for (int mt = 0; mt < 4; mt++)
#pragma unroll
                for (int nt = 0; nt < 4; nt++)
                    acc[mt][nt] = __builtin_amdgcn_mfma_f32_16x16x32_bf16(
                        af[mt], bf[nt], acc[mt][nt], 0, 0, 0);
        }
        __syncthreads();
    }
}

// ------------------------------------------------------- QKV projection GEMM
// z = 0/1/2 -> Q/K/V. Output layout [b,h,s,PDP] bf16 (d padded; pads pre-zeroed).
// Q additionally scaled by QSCALE so attention softmax is a bare exp2.
__global__ __launch_bounds__(256) void gemm_qkv_kernel(
    const unsigned short* __restrict__ Xb, const unsigned short* __restrict__ Wtall,
    const float* __restrict__ bq, const float* __restrict__ bk,
    const float* __restrict__ bv, unsigned short* __restrict__ QKV) {
    __shared__ __align__(16) unsigned short Asm[128 * 64];
    __shared__ __align__(16) unsigned short Bsm[128 * 64];
    const int z = blockIdx.z;
    const int m0 = blockIdx.y * 128, n0 = blockIdx.x * 128;
    const float* bias = (z == 0) ? bq : (z == 1) ? bk : bv;
    const float vscale = (z == 0) ? QSCALE : 1.0f;
    floatx4 acc[4][4];
    gemm_core(Xb + (long)m0 * D_, Wtall + (long)z * D_ * D_ + (long)n0 * D_, Asm, Bsm, acc);

    unsigned short* out = QKV + (long)z * BH_ * S_ * PDP;
    const int tid = threadIdx.x, lane = tid & 63, w = tid >> 6;
    const int wr = (w >> 1) * 64, wc = (w & 1) * 64;
    const int l15 = lane & 15, l4 = lane >> 4;
#pragma unroll
    for (int nt = 0; nt < 4; nt++) {
        int n = n0 + wc + nt * 16 + l15;
        int h = n / PD_, pd = n % PD_;
        float bb = bias[n];
#pragma unroll
        for (int mt = 0; mt < 4; mt++) {
#pragma unroll
            for (int r = 0; r < 4; r++) {
                int m = m0 + wr + mt * 16 + l4 * 4 + r;
                int b = m >> 10, s = m & 1023;
                out[((long)(b * H_ + h) * S_ + s) * PDP + pd] = f2bf((acc[mt][nt][r] + bb) * vscale);
            }
        }
    }
}

// --------------------------------------------- V transpose: [bh,s,64]->[bh,64,s]
// Also writes the l-accumulator ones-column at d=48 and zeros at d=49..63.
__global__ __launch_bounds__(256) void transpose_v_kernel(
    const unsigned short* __restrict__ V, unsigned short* __restrict__ Vt) {
    __shared__ __align__(16) unsigned short T[64 * 64];  // [s][d] swizzled
    const int tid = threadIdx.x;
    const int st = blockIdx.x * 64, bh = blockIdx.y;
    const unsigned short* src = V + (long)bh * S_ * PDP;
    unsigned short* dst = Vt + (long)bh * PDP * S_;
#pragma unroll
    for (int i = 0; i < 2; i++) {
        int c = tid + i * 256;
        int row = c >> 3, seg = c & 7;
        *(uint4*)&T[row * 64 + ((seg ^ (row & 7)) * 8)] =
            *(const uint4*)&src[(long)(st + row) * PDP + seg * 8];
    }
    __syncthreads();
    const int d = tid >> 2;
    unsigned short tmp[16];
#pragma unroll
    for (int j = 0; j < 16; j++) {
        int sl = (tid & 3) * 16 + j;
        unsigned short v = T[sl * 64 + ((d >> 3) ^ (sl & 7)) * 8 + (d & 7)];
        tmp[j] = (d < PD_) ? v : ((d == PD_) ? (unsigned short)0x3F80 : (unsigned short)0);
    }
    *(uint4*)&dst[(long)d * S_ + st + (tid & 3) * 16] = *(uint4*)&tmp[0];
    *(uint4*)&dst[(long)d * S_ + st + (tid & 3) * 16 + 8] = *(uint4*)&tmp[8];
}

// --------------------------------------------------------- output projection
__global__ __launch_bounds__(256) void gemm_out_kernel(
    const unsigned short* __restrict__ Ctx, const unsigned short* __restrict__ Wot,
    const float* __restrict__ bo, float* __restrict__ Out) {
    __shared__ __align__(16) unsigned short Asm[128 * 64];
    __shared__ __align__(16) unsigned short Bsm[128 * 64];
    const int m0 = blockIdx.y * 128, n0 = blockIdx.x * 128;
    floatx4 acc[4][4];
    gemm_core(Ctx + (long)m0 * D_, Wot + (long)n0 * D_, Asm, Bsm, acc);

    const int tid = threadIdx.x, lane = tid & 63, w = tid >> 6;
    const int wr = (w >> 1) * 64, wc = (w & 1) * 64;
    const int l15 = lane & 15, l4 = lane >> 4;
#pragma unroll
    for (int nt = 0; nt < 4; nt++) {
        int n = n0 + wc + nt * 16 + l15;
        float bb = bo[n];
#pragma unroll
        for (int mt = 0; mt < 4; mt++) {
#pragma unroll
            for (int r = 0; r < 4; r++) {
                int m = m0 + wr + mt * 16 + l4 * 4 + r;
                Out[(long)m * D_ + n] = acc[mt][nt][r] + bb;
            }
        }
    }
}

// ------------------------------------------------------------ flash attention
// One block = (b,h) x 64-query tile; 4 waves x 16 queries each.
// Scores computed transposed (S^T = K*Q^T) so P rows pack into b64 LDS writes.
// Fixed-max softmax: P = exp2(score) (scale*log2e pre-folded into Q).
// l obtained via the ones-column at V^T row d=48 (accO[3], lane l15==0).
__global__ __launch_bounds__(256) void attn_kernel(
    const unsigned short* __restrict__ Qg, const unsigned short* __restrict__ Kg,
    const unsigned short* __restrict__ Vtg, unsigned short* __restrict__ Ctx) {
    __shared__ __align__(16) unsigned short Ks[64 * 64];   // [key][d] swizzled
    __shared__ __align__(16) unsigned short Vs[64 * 64];   // [d][key] swizzled
    __shared__ __align__(16) unsigned short Ps[4][16 * 64]; // per-wave [q][key] swizzled
    const int tid = threadIdx.x, lane = tid & 63, w = tid >> 6;
    const int l15 = lane & 15, l4 = lane >> 4;
    const int qt = blockIdx.x, bh = blockIdx.y;
    const long qkbase = (long)bh * S_ * PDP;   // Q/K: [bh][s][64]
    const long vbase  = (long)bh * PDP * S_;   // Vt:  [bh][d][1024]

    // Q B-fragments straight from global (q = qt*64 + w*16 + l15)
    const int qrow = qt * 64 + w * 16 + l15;
    short8 bq0 = *(const short8*)&Qg[qkbase + (long)qrow * PDP + l4 * 8];
    short8 bq1 = *(const short8*)&Qg[qkbase + (long)qrow * PDP + 32 + l4 * 8];

    const floatx4 zero = {0.f, 0.f, 0.f, 0.f};
    floatx4 accO[4];
#pragma unroll
    for (int nt = 0; nt < 4; nt++) accO[nt] = zero;

    unsigned short* Pw = &Ps[w][0];

    for (int kt = 0; kt < 16; kt++) {
        __syncthreads();
        // stage K tile [key][d] and V^T tile [d][key]: 8 KB each, vectorized
#pragma unroll
        for (int i = 0; i < 2; i++) {
            int c = tid + i * 256;
            int row = c >> 3, seg = c & 7;
            int ps = row * 64 + ((seg ^ (row & 7)) * 8);
            *(uint4*)&Ks[ps] = *(const uint4*)&Kg[qkbase + (long)(kt * 64 + row) * PDP + seg * 8];
            *(uint4*)&Vs[ps] = *(const uint4*)&Vtg[vbase + (long)row * S_ + kt * 64 + seg * 8];
        }
        __syncthreads();

        // S^T[key][q]: A = K (16 keys per subtile), B = Q frags
        floatx4 sc[4];
#pragma unroll
        for (int ks = 0; ks < 4; ks++) {
            int kr = ks * 16 + l15;
            short8 a0 = *(const short8*)&Ks[kr * 64 + ((0 + l4) ^ (kr & 7)) * 8];
            short8 a1 = *(const short8*)&Ks[kr * 64 + ((4 + l4) ^ (kr & 7)) * 8];
            floatx4 a = zero;
            a = __builtin_amdgcn_mfma_f32_16x16x32_bf16(a0, bq0, a, 0, 0, 0);
            a = __builtin_amdgcn_mfma_f32_16x16x32_bf16(a1, bq1, a, 0, 0, 0);
            sc[ks] = a;
        }

        // P = exp2(S) ; pack 4 contiguous keys (r=0..3) -> one b64 LDS write
#pragma unroll
        for (int ks = 0; ks < 4; ks++) {
            unsigned short p4[4];
#pragma unroll
            for (int r = 0; r < 4; r++) p4[r] = f2bf(__builtin_amdgcn_exp2f(sc[ks][r]));
            int addr = l15 * 64 + (((ks * 2 + (l4 >> 1)) ^ (l15 & 7)) * 8) + (l4 & 1) * 4;
            *(uint2*)&Pw[addr] = *(uint2*)&p4[0];
        }

        // PV: A = P frag (vectorized b128), B = V^T frags
#pragma unroll
        for (int kk = 0; kk < 2; kk++) {
            short8 ap = *(const short8*)&Pw[l15 * 64 + (((kk * 4 + l4) ^ (l15 & 7)) * 8)];
#pragma unroll
            for (int nt = 0; nt < 4; nt++) {
                int vr = nt * 16 + l15;
                short8 bv8 = *(const short8*)&Vs[vr * 64 + (((kk * 4 + l4) ^ (vr & 7)) * 8)];
                accO[nt] = __builtin_amdgcn_mfma_f32_16x16x32_bf16(ap, bv8, accO[nt], 0, 0, 0);
            }
        }
    }

    // epilogue: l = accO[3] at lane l15==0 (d=48 ones-column); out = accO/l
    const int b = bh >> 4, h = bh & 15;
#pragma unroll
    for (int r = 0; r < 4; r++) {
        float lsum = __shfl(accO[3][r], lane & 48);
        float inv = 1.0f / lsum;
        int q = qt * 64 + w * 16 + l4 * 4 + r;
        long rowoff = (long)(b * S_ + q) * D_ + h * PD_;
#pragma unroll
        for (int nt = 0; nt < 3; nt++)
            Ctx[rowoff + nt * 16 + l15] = f2bf(accO[nt][r] * inv);
    }
}

// ---------------------------------------------------------------------------
extern "C" void kernel_launch(void* const* d_in, const int* in_sizes, int n_in,
                              void* d_out, int out_size, void* d_ws, size_t ws_size,
                              hipStream_t stream) {
    const float* X  = (const float*)d_in[0];
    const float* Wq = (const float*)d_in[1];
    const float* bq = (const float*)d_in[2];
    const float* Wk = (const float*)d_in[3];
    const float* bk = (const float*)d_in[4];
    const float* Wv = (const float*)d_in[5];
    const float* bv = (const float*)d_in[6];
    const float* Wo = (const float*)d_in[7];
    const float* bo = (const float*)d_in[8];

    unsigned char* ws = (unsigned char*)d_ws;
    const long XB_BYTES  = (long)M_ * D_ * 2;         // 12,582,912
    const long WT_BYTES  = (long)D_ * D_ * 2;         // 1,179,648
    const long QKV_BYTES = (long)BH_ * S_ * PDP * 2;  // 16,777,216

    unsigned short* Xbf   = (unsigned short*)(ws);
    unsigned short* Wtall = (unsigned short*)(ws + XB_BYTES);
    unsigned short* Qws   = (unsigned short*)(ws + XB_BYTES + 4 * WT_BYTES);
    unsigned short* Kws   = Qws + QKV_BYTES / 2;
    unsigned short* Vws   = Kws + QKV_BYTES / 2;
    unsigned short* Vtws  = Vws + QKV_BYTES / 2;
    unsigned short* Ctx   = Vws;  // aliases V (dead after transpose_v)

    // zero Q and K pads (d=48..63 never written by GEMM; must be 0 for K*Q^T)
    hipMemsetAsync(Qws, 0, 2 * QKV_BYTES, stream);

    convert_x_kernel<<<(M_ * D_) / (256 * 4), 256, 0, stream>>>(X, Xbf);
    transpose_w_kernel<<<dim3(24, 24, 4), dim3(32, 8), 0, stream>>>(Wq, Wk, Wv, Wo, Wtall);
    gemm_qkv_kernel<<<dim3(6, 64, 3), 256, 0, stream>>>(Xbf, Wtall, bq, bk, bv, Qws);
    transpose_v_kernel<<<dim3(16, 128), 256, 0, stream>>>(Vws, Vtws);
    attn_kernel<<<dim3(16, 128), 256, 0, stream>>>(Qws, Kws, Vtws, Ctx);
    gemm_out_kernel<<<dim3(6, 64), 256, 0, stream>>>(
        Ctx, Wtall + 3 * (WT_BYTES / 2), bo, (float*)d_out);
}

// Round 3
// 219.622 us; speedup vs baseline: 1.4774x; 1.1351x over previous
//
#include <hip/hip_runtime.h>
#include <hip/hip_bf16.h>

// Problem constants
#define B_   8
#define S_   1024
#define D_   768
#define H_   16
#define PD_  48
#define PDP  64        // padded per-head dim
#define M_   8192      // B*S
#define BH_  128       // B*H

// 1/sqrt(48) * log2(e)  -> folded into Q so softmax is a bare v_exp (exp2)
#define QSCALE 0.20823031f

typedef __attribute__((ext_vector_type(8))) short short8;
typedef __attribute__((ext_vector_type(4))) float floatx4;

__device__ __forceinline__ unsigned short f2bf(float f) {
    __hip_bfloat16 h = __float2bfloat16(f);
    return *reinterpret_cast<unsigned short*>(&h);
}

// async 16B global -> LDS (direct, no VGPR round trip). LDS dest must be
// wave-uniform base + lane*16; any swizzle must be folded into the GLOBAL addr.
__device__ __forceinline__ void async_copy16(const unsigned short* gptr, unsigned short* lptr) {
    __builtin_amdgcn_global_load_lds(
        (const __attribute__((address_space(1))) unsigned int*)gptr,
        (__attribute__((address_space(3))) unsigned int*)lptr, 16, 0, 0);
}

// ---------------------------------------------------------------- convert X
__global__ __launch_bounds__(256) void convert_x_kernel(
    const float* __restrict__ X, unsigned short* __restrict__ Xb) {
    long i = ((long)blockIdx.x * 256 + threadIdx.x) * 4;
    float4 v = *(const float4*)(X + i);
    ushort4 o;
    o.x = f2bf(v.x); o.y = f2bf(v.y); o.z = f2bf(v.z); o.w = f2bf(v.w);
    *(ushort4*)(Xb + i) = o;
}

// ------------------------------------------------- transpose + cast weights
__global__ __launch_bounds__(256) void transpose_w_kernel(
    const float* __restrict__ w0, const float* __restrict__ w1,
    const float* __restrict__ w2, const float* __restrict__ w3,
    unsigned short* __restrict__ Wtall) {
    __shared__ float tile[32][33];
    const int tx = threadIdx.x, ty = threadIdx.y;
    const int nt = blockIdx.x * 32, kt = blockIdx.y * 32, z = blockIdx.z;
    const float* W = (z == 0) ? w0 : (z == 1) ? w1 : (z == 2) ? w2 : w3;
    unsigned short* Wt = Wtall + (long)z * D_ * D_;
#pragma unroll
    for (int i = 0; i < 4; i++)
        tile[ty + i * 8][tx] = W[(long)(kt + ty + i * 8) * D_ + nt + tx];
    __syncthreads();
#pragma unroll
    for (int i = 0; i < 4; i++)
        Wt[(long)(nt + ty + i * 8) * D_ + kt + tx] = f2bf(tile[tx][ty + i * 8]);
}

// --------------------------------------------------------------- GEMM core
// C[128x128] = A[128xK] * Bt[128xK]^T, bf16 in, fp32 acc.
// LDS XOR-swizzle: LDS chunk (row, seg_sw) holds global seg = seg_sw ^ (row&7).
// Staging via global_load_lds: LDS side is lane-linear; swizzle folded into
// the per-lane global address (permutation within each 128B row).
__device__ __forceinline__ void gemm_core(
    const unsigned short* __restrict__ Ag,   // A rows at m0, stride D_
    const unsigned short* __restrict__ Btg,  // Bt rows at n0, stride D_
    unsigned short* Asm, unsigned short* Bsm, floatx4 acc[4][4]) {
    const int tid = threadIdx.x;
    const int lane = tid & 63, w = tid >> 6;
    const int wr = (w >> 1) * 64, wc = (w & 1) * 64;
    const int l15 = lane & 15, l4 = lane >> 4;
    const floatx4 zero = {0.f, 0.f, 0.f, 0.f};
#pragma unroll
    for (int mt = 0; mt < 4; mt++)
#pragma unroll
        for (int nt = 0; nt < 4; nt++) acc[mt][nt] = zero;

    for (int kb = 0; kb < D_; kb += 64) {
#pragma unroll
        for (int i = 0; i < 4; i++) {
            int c = tid + i * 256;
            int row = c >> 3, seg = (c & 7) ^ (row & 7);
            long goff = (long)row * D_ + kb + seg * 8;
            async_copy16(&Ag[goff], &Asm[c * 8]);
            async_copy16(&Btg[goff], &Bsm[c * 8]);
        }
        __syncthreads();
#pragma unroll
        for (int kk = 0; kk < 2; kk++) {
            short8 af[4], bf[4];
#pragma unroll
            for (int mt = 0; mt < 4; mt++) {
                int r = wr + mt * 16 + l15;
                af[mt] = *(const short8*)&Asm[r * 64 + (((kk * 4 + l4) ^ (r & 7)) * 8)];
            }
#pragma unroll
            for (int nt = 0; nt < 4; nt++) {
                int c = wc + nt * 16 + l15;
                bf[nt] = *(const short8*)&Bsm[c * 64 + (((kk * 4 + l4) ^ (c & 7)) * 8)];
            }
#pragma unroll
            for (int mt = 0; mt < 4; mt++)
#pragma unroll
                for (int nt = 0; nt < 4; nt++)
                    acc[mt][nt] = __builtin_amdgcn_mfma_f32_16x16x32_bf16(
                        af[mt], bf[nt], acc[mt][nt], 0, 0, 0);
        }
        __syncthreads();
    }
}

// ------------------------------------------------------- QKV projection GEMM
// z = 0/1/2 -> Q/K/V. Output layout [b,h,s,PDP] bf16 (d padded; pads pre-zeroed).
// Q additionally scaled by QSCALE so attention softmax is a bare exp2.
__global__ __launch_bounds__(256) void gemm_qkv_kernel(
    const unsigned short* __restrict__ Xb, const unsigned short* __restrict__ Wtall,
    const float* __restrict__ bq, const float* __restrict__ bk,
    const float* __restrict__ bv, unsigned short* __restrict__ QKV) {
    __shared__ __align__(16) unsigned short Asm[128 * 64];
    __shared__ __align__(16) unsigned short Bsm[128 * 64];
    const int z = blockIdx.z;
    const int m0 = blockIdx.y * 128, n0 = blockIdx.x * 128;
    const float* bias = (z == 0) ? bq : (z == 1) ? bk : bv;
    const float vscale = (z == 0) ? QSCALE : 1.0f;
    floatx4 acc[4][4];
    gemm_core(Xb + (long)m0 * D_, Wtall + (long)z * D_ * D_ + (long)n0 * D_, Asm, Bsm, acc);

    unsigned short* out = QKV + (long)z * BH_ * S_ * PDP;
    const int tid = threadIdx.x, lane = tid & 63, w = tid >> 6;
    const int wr = (w >> 1) * 64, wc = (w & 1) * 64;
    const int l15 = lane & 15, l4 = lane >> 4;
#pragma unroll
    for (int nt = 0; nt < 4; nt++) {
        int n = n0 + wc + nt * 16 + l15;
        int h = n / PD_, pd = n % PD_;
        float bb = bias[n];
#pragma unroll
        for (int mt = 0; mt < 4; mt++) {
#pragma unroll
            for (int r = 0; r < 4; r++) {
                int m = m0 + wr + mt * 16 + l4 * 4 + r;
                int b = m >> 10, s = m & 1023;
                out[((long)(b * H_ + h) * S_ + s) * PDP + pd] = f2bf((acc[mt][nt][r] + bb) * vscale);
            }
        }
    }
}

// --------------------------------------------- V transpose: [bh,s,64]->[bh,64,s]
// Also writes the l-accumulator ones-column at d=48 and zeros at d=49..63.
__global__ __launch_bounds__(256) void transpose_v_kernel(
    const unsigned short* __restrict__ V, unsigned short* __restrict__ Vt) {
    __shared__ __align__(16) unsigned short T[64 * 64];  // [s][d] swizzled
    const int tid = threadIdx.x;
    const int st = blockIdx.x * 64, bh = blockIdx.y;
    const unsigned short* src = V + (long)bh * S_ * PDP;
    unsigned short* dst = Vt + (long)bh * PDP * S_;
#pragma unroll
    for (int i = 0; i < 2; i++) {
        int c = tid + i * 256;
        int row = c >> 3, seg = (c & 7) ^ (row & 7);
        async_copy16(&src[(long)(st + row) * PDP + seg * 8], &T[c * 8]);
    }
    __syncthreads();
    const int d = tid >> 2;
    unsigned short tmp[16];
#pragma unroll
    for (int j = 0; j < 16; j++) {
        int sl = (tid & 3) * 16 + j;
        unsigned short v = T[sl * 64 + ((d >> 3) ^ (sl & 7)) * 8 + (d & 7)];
        tmp[j] = (d < PD_) ? v : ((d == PD_) ? (unsigned short)0x3F80 : (unsigned short)0);
    }
    *(uint4*)&dst[(long)d * S_ + st + (tid & 3) * 16] = *(uint4*)&tmp[0];
    *(uint4*)&dst[(long)d * S_ + st + (tid & 3) * 16 + 8] = *(uint4*)&tmp[8];
}

// --------------------------------------------------------- output projection
__global__ __launch_bounds__(256) void gemm_out_kernel(
    const unsigned short* __restrict__ Ctx, const unsigned short* __restrict__ Wot,
    const float* __restrict__ bo, float* __restrict__ Out) {
    __shared__ __align__(16) unsigned short Asm[128 * 64];
    __shared__ __align__(16) unsigned short Bsm[128 * 64];
    const int m0 = blockIdx.y * 128, n0 = blockIdx.x * 128;
    floatx4 acc[4][4];
    gemm_core(Ctx + (long)m0 * D_, Wot + (long)n0 * D_, Asm, Bsm, acc);

    const int tid = threadIdx.x, lane = tid & 63, w = tid >> 6;
    const int wr = (w >> 1) * 64, wc = (w & 1) * 64;
    const int l15 = lane & 15, l4 = lane >> 4;
#pragma unroll
    for (int nt = 0; nt < 4; nt++) {
        int n = n0 + wc + nt * 16 + l15;
        float bb = bo[n];
#pragma unroll
        for (int mt = 0; mt < 4; mt++) {
#pragma unroll
            for (int r = 0; r < 4; r++) {
                int m = m0 + wr + mt * 16 + l4 * 4 + r;
                Out[(long)m * D_ + n] = acc[mt][nt][r] + bb;
            }
        }
    }
}

// ------------------------------------------------------------ flash attention
// One block = (b,h) x 128-query tile; 4 waves x 32 queries (2 groups of 16).
// Scores computed transposed (S^T = K*Q^T); fixed-max softmax P = exp2(score)
// (scale*log2e pre-folded into Q). l via ones-column at V^T row d=48.
// K A-frags shared across both query groups; K/V staged via global_load_lds.
__global__ __launch_bounds__(256, 4) void attn_kernel(
    const unsigned short* __restrict__ Qg, const unsigned short* __restrict__ Kg,
    const unsigned short* __restrict__ Vtg, unsigned short* __restrict__ Ctx) {
    __shared__ __align__(16) unsigned short Ks[64 * 64];    // [key][d] swizzled
    __shared__ __align__(16) unsigned short Vs[64 * 64];    // [d][key] swizzled
    __shared__ __align__(16) unsigned short Ps[4][16 * 64]; // per-wave [q][key] swizzled
    const int tid = threadIdx.x, lane = tid & 63, w = tid >> 6;
    const int l15 = lane & 15, l4 = lane >> 4;
    const int qt = blockIdx.x, bh = blockIdx.y;
    const long qkbase = (long)bh * S_ * PDP;   // Q/K: [bh][s][64]
    const long vbase  = (long)bh * PDP * S_;   // Vt:  [bh][d][1024]

    // Q B-fragments straight from global; wave w owns queries w*32..w*32+31
    short8 bq[2][2];
#pragma unroll
    for (int g = 0; g < 2; g++) {
        int qrow = qt * 128 + w * 32 + g * 16 + l15;
        bq[g][0] = *(const short8*)&Qg[qkbase + (long)qrow * PDP + l4 * 8];
        bq[g][1] = *(const short8*)&Qg[qkbase + (long)qrow * PDP + 32 + l4 * 8];
    }

    const floatx4 zero = {0.f, 0.f, 0.f, 0.f};
    floatx4 accO[2][4];
#pragma unroll
    for (int g = 0; g < 2; g++)
#pragma unroll
        for (int nt = 0; nt < 4; nt++) accO[g][nt] = zero;

    unsigned short* Pw = &Ps[w][0];

    for (int kt = 0; kt < 16; kt++) {
        __syncthreads();
        // stage K [key][d] and V^T [d][key] tiles: 8KB each, direct-to-LDS
#pragma unroll
        for (int i = 0; i < 2; i++) {
            int c = tid + i * 256;
            int row = c >> 3, seg = (c & 7) ^ (row & 7);
            async_copy16(&Kg[qkbase + (long)(kt * 64 + row) * PDP + seg * 8], &Ks[c * 8]);
            async_copy16(&Vtg[vbase + (long)row * S_ + kt * 64 + seg * 8], &Vs[c * 8]);
        }
        __syncthreads();

        // K A-frags, shared across both query groups
        short8 ak[4][2];
#pragma unroll
        for (int ks = 0; ks < 4; ks++) {
            int kr = ks * 16 + l15;
            ak[ks][0] = *(const short8*)&Ks[kr * 64 + ((l4 ^ (kr & 7)) * 8)];
            ak[ks][1] = *(const short8*)&Ks[kr * 64 + (((4 + l4) ^ (kr & 7)) * 8)];
        }

#pragma unroll
        for (int g = 0; g < 2; g++) {
            // S^T[key][q]
            floatx4 sc[4];
#pragma unroll
            for (int ks = 0; ks < 4; ks++) {
                floatx4 a = zero;
                a = __builtin_amdgcn_mfma_f32_16x16x32_bf16(ak[ks][0], bq[g][0], a, 0, 0, 0);
                a = __builtin_amdgcn_mfma_f32_16x16x32_bf16(ak[ks][1], bq[g][1], a, 0, 0, 0);
                sc[ks] = a;
            }
            // P = exp2(S); pack 4 contiguous keys -> one b64 LDS write
#pragma unroll
            for (int ks = 0; ks < 4; ks++) {
                unsigned short p4[4];
#pragma unroll
                for (int r = 0; r < 4; r++) p4[r] = f2bf(__builtin_amdgcn_exp2f(sc[ks][r]));
                int addr = l15 * 64 + (((ks * 2 + (l4 >> 1)) ^ (l15 & 7)) * 8) + (l4 & 1) * 4;
                *(uint2*)&Pw[addr] = *(uint2*)&p4[0];
            }
            // PV
#pragma unroll
            for (int kk = 0; kk < 2; kk++) {
                short8 ap = *(const short8*)&Pw[l15 * 64 + (((kk * 4 + l4) ^ (l15 & 7)) * 8)];
#pragma unroll
                for (int nt = 0; nt < 4; nt++) {
                    int vr = nt * 16 + l15;
                    short8 bv8 = *(const short8*)&Vs[vr * 64 + (((kk * 4 + l4) ^ (vr & 7)) * 8)];
                    accO[g][nt] = __builtin_amdgcn_mfma_f32_16x16x32_bf16(ap, bv8, accO[g][nt], 0, 0, 0);
                }
            }
        }
    }

    // epilogue: l = accO[g][3] at l15==0 (d=48 ones-column); out = accO/l
    const int b = bh >> 4, h = bh & 15;
#pragma unroll
    for (int g = 0; g < 2; g++) {
#pragma unroll
        for (int r = 0; r < 4; r++) {
            float lsum = __shfl(accO[g][3][r], lane & 48);
            float inv = 1.0f / lsum;
            int q = qt * 128 + w * 32 + g * 16 + l4 * 4 + r;
            long rowoff = (long)(b * S_ + q) * D_ + h * PD_;
#pragma unroll
            for (int nt = 0; nt < 3; nt++)
                Ctx[rowoff + nt * 16 + l15] = f2bf(accO[g][nt][r] * inv);
        }
    }
}

// ---------------------------------------------------------------------------
extern "C" void kernel_launch(void* const* d_in, const int* in_sizes, int n_in,
                              void* d_out, int out_size, void* d_ws, size_t ws_size,
                              hipStream_t stream) {
    const float* X  = (const float*)d_in[0];
    const float* Wq = (const float*)d_in[1];
    const float* bq = (const float*)d_in[2];
    const float* Wk = (const float*)d_in[3];
    const float* bk = (const float*)d_in[4];
    const float* Wv = (const float*)d_in[5];
    const float* bv = (const float*)d_in[6];
    const float* Wo = (const float*)d_in[7];
    const float* bo = (const float*)d_in[8];

    unsigned char* ws = (unsigned char*)d_ws;
    const long XB_BYTES  = (long)M_ * D_ * 2;         // 12,582,912
    const long WT_BYTES  = (long)D_ * D_ * 2;         // 1,179,648
    const long QKV_BYTES = (long)BH_ * S_ * PDP * 2;  // 16,777,216

    unsigned short* Xbf   = (unsigned short*)(ws);
    unsigned short* Wtall = (unsigned short*)(ws + XB_BYTES);
    unsigned short* Qws   = (unsigned short*)(ws + XB_BYTES + 4 * WT_BYTES);
    unsigned short* Kws   = Qws + QKV_BYTES / 2;
    unsigned short* Vws   = Kws + QKV_BYTES / 2;
    unsigned short* Vtws  = Vws + QKV_BYTES / 2;
    unsigned short* Ctx   = Vws;  // aliases V (dead after transpose_v)

    // zero Q and K pads (d=48..63 never written by GEMM; must be 0 for K*Q^T)
    hipMemsetAsync(Qws, 0, 2 * QKV_BYTES, stream);

    convert_x_kernel<<<(M_ * D_) / (256 * 4), 256, 0, stream>>>(X, Xbf);
    transpose_w_kernel<<<dim3(24, 24, 4), dim3(32, 8), 0, stream>>>(Wq, Wk, Wv, Wo, Wtall);
    gemm_qkv_kernel<<<dim3(6, 64, 3), 256, 0, stream>>>(Xbf, Wtall, bq, bk, bv, Qws);
    transpose_v_kernel<<<dim3(16, 128), 256, 0, stream>>>(Vws, Vtws);
    attn_kernel<<<dim3(8, 128), 256, 0, stream>>>(Qws, Kws, Vtws, Ctx);
    gemm_out_kernel<<<dim3(6, 64), 256, 0, stream>>>(
        Ctx, Wtall + 3 * (WT_BYTES / 2), bo, (float*)d_out);
}

// Round 4
// 195.933 us; speedup vs baseline: 1.6560x; 1.1209x over previous
//
#include <hip/hip_runtime.h>
#include <hip/hip_bf16.h>

// Problem constants
#define B_   8
#define S_   1024
#define D_   768
#define H_   16
#define PD_  48
#define PDP  64        // padded per-head dim
#define M_   8192      // B*S
#define BH_  128       // B*H

// 1/sqrt(48) * log2(e)  -> folded into Q so softmax is a bare exp2
#define QSCALE 0.20823031f

typedef __attribute__((ext_vector_type(8))) short short8;
typedef __attribute__((ext_vector_type(4))) float floatx4;

__device__ __forceinline__ unsigned short f2bf(float f) {
    __hip_bfloat16 h = __float2bfloat16(f);
    return *reinterpret_cast<unsigned short*>(&h);
}

// async 16B global -> LDS (direct, no VGPR round trip). LDS dest must be
// wave-uniform base + lane*16; any swizzle must be folded into the GLOBAL addr.
__device__ __forceinline__ void async_copy16(const unsigned short* gptr, unsigned short* lptr) {
    __builtin_amdgcn_global_load_lds(
        (const __attribute__((address_space(1))) unsigned int*)gptr,
        (__attribute__((address_space(3))) unsigned int*)lptr, 16, 0, 0);
}

// ---------------------------------------- fused: convert X + transpose weights
// blocks [0,6144): cast X tile to bf16. blocks [6144,8448): W transpose+cast.
__global__ __launch_bounds__(256) void prep_kernel(
    const float* __restrict__ X, unsigned short* __restrict__ Xb,
    const float* __restrict__ w0, const float* __restrict__ w1,
    const float* __restrict__ w2, const float* __restrict__ w3,
    unsigned short* __restrict__ Wtall) {
    __shared__ float tile[32][33];
    const int tid = threadIdx.x;
    const int bx = blockIdx.x;
    if (bx < 6144) {
        long i = ((long)bx * 256 + tid) * 4;
        float4 v = *(const float4*)(X + i);
        ushort4 o;
        o.x = f2bf(v.x); o.y = f2bf(v.y); o.z = f2bf(v.z); o.w = f2bf(v.w);
        *(ushort4*)(Xb + i) = o;
        return;
    }
    const int t = bx - 6144;
    const int z = t / 576, r = t % 576;
    const int nt = (r % 24) * 32, kt = (r / 24) * 32;
    const int tx = tid & 31, ty = tid >> 5;
    const float* W = (z == 0) ? w0 : (z == 1) ? w1 : (z == 2) ? w2 : w3;
    unsigned short* Wt = Wtall + (long)z * D_ * D_;
#pragma unroll
    for (int i = 0; i < 4; i++)
        tile[ty + i * 8][tx] = W[(long)(kt + ty + i * 8) * D_ + nt + tx];
    __syncthreads();
#pragma unroll
    for (int i = 0; i < 4; i++)
        Wt[(long)(nt + ty + i * 8) * D_ + kt + tx] = f2bf(tile[tx][ty + i * 8]);
}

// --------------------------------------------------------------- GEMM core
// C[128x128] = A[128xK] * Bt[128xK]^T, bf16 in, fp32 acc.
// LDS XOR-swizzle: LDS chunk (row, seg_sw) holds global seg = seg_sw ^ (row&7).
__device__ __forceinline__ void gemm_core(
    const unsigned short* __restrict__ Ag,   // A rows at m0, stride D_
    const unsigned short* __restrict__ Btg,  // Bt rows at n0, stride D_
    unsigned short* Asm, unsigned short* Bsm, floatx4 acc[4][4]) {
    const int tid = threadIdx.x;
    const int lane = tid & 63, w = tid >> 6;
    const int wr = (w >> 1) * 64, wc = (w & 1) * 64;
    const int l15 = lane & 15, l4 = lane >> 4;
    const floatx4 zero = {0.f, 0.f, 0.f, 0.f};
#pragma unroll
    for (int mt = 0; mt < 4; mt++)
#pragma unroll
        for (int nt = 0; nt < 4; nt++) acc[mt][nt] = zero;

    for (int kb = 0; kb < D_; kb += 64) {
#pragma unroll
        for (int i = 0; i < 4; i++) {
            int c = tid + i * 256;
            int row = c >> 3, seg = (c & 7) ^ (row & 7);
            long goff = (long)row * D_ + kb + seg * 8;
            async_copy16(&Ag[goff], &Asm[c * 8]);
            async_copy16(&Btg[goff], &Bsm[c * 8]);
        }
        __syncthreads();
#pragma unroll
        for (int kk = 0; kk < 2; kk++) {
            short8 af[4], bf[4];
#pragma unroll
            for (int mt = 0; mt < 4; mt++) {
                int r = wr + mt * 16 + l15;
                af[mt] = *(const short8*)&Asm[r * 64 + (((kk * 4 + l4) ^ (r & 7)) * 8)];
            }
#pragma unroll
            for (int nt = 0; nt < 4; nt++) {
                int c = wc + nt * 16 + l15;
                bf[nt] = *(const short8*)&Bsm[c * 64 + (((kk * 4 + l4) ^ (c & 7)) * 8)];
            }
#pragma unroll
            for (int mt = 0; mt < 4; mt++)
#pragma unroll
                for (int nt = 0; nt < 4; nt++)
                    acc[mt][nt] = __builtin_amdgcn_mfma_f32_16x16x32_bf16(
                        af[mt], bf[nt], acc[mt][nt], 0, 0, 0);
        }
        __syncthreads();
    }
}

// ------------------------------------------------------- QKV projection GEMM
// Grid: x = m-block (64), y = n-block (6), z = Q/K/V. m-major => per-XCD L2
// pins 8 A-tiles; one B-tile streams at a time.
__global__ __launch_bounds__(256) void gemm_qkv_kernel(
    const unsigned short* __restrict__ Xb, const unsigned short* __restrict__ Wtall,
    const float* __restrict__ bq, const float* __restrict__ bk,
    const float* __restrict__ bv, unsigned short* __restrict__ QKV) {
    __shared__ __align__(16) unsigned short Asm[128 * 64];
    __shared__ __align__(16) unsigned short Bsm[128 * 64];
    const int z = blockIdx.z;
    const int m0 = blockIdx.x * 128, n0 = blockIdx.y * 128;
    const float* bias = (z == 0) ? bq : (z == 1) ? bk : bv;
    const float vscale = (z == 0) ? QSCALE : 1.0f;
    floatx4 acc[4][4];
    gemm_core(Xb + (long)m0 * D_, Wtall + (long)z * D_ * D_ + (long)n0 * D_, Asm, Bsm, acc);

    unsigned short* out = QKV + (long)z * BH_ * S_ * PDP;
    const int tid = threadIdx.x, lane = tid & 63, w = tid >> 6;
    const int wr = (w >> 1) * 64, wc = (w & 1) * 64;
    const int l15 = lane & 15, l4 = lane >> 4;
#pragma unroll
    for (int nt = 0; nt < 4; nt++) {
        int n = n0 + wc + nt * 16 + l15;
        int h = n / PD_, pd = n % PD_;
        float bb = bias[n];
#pragma unroll
        for (int mt = 0; mt < 4; mt++) {
#pragma unroll
            for (int r = 0; r < 4; r++) {
                int m = m0 + wr + mt * 16 + l4 * 4 + r;
                int b = m >> 10, s = m & 1023;
                out[((long)(b * H_ + h) * S_ + s) * PDP + pd] = f2bf((acc[mt][nt][r] + bb) * vscale);
            }
        }
    }
}

// --------------------------------------------- V transpose: [bh,s,64]->[bh,64,s]
// Also writes the l-accumulator ones-column at d=48 and zeros at d=49..63.
__global__ __launch_bounds__(256) void transpose_v_kernel(
    const unsigned short* __restrict__ V, unsigned short* __restrict__ Vt) {
    __shared__ __align__(16) unsigned short T[64 * 64];  // [s][d] swizzled
    const int tid = threadIdx.x;
    const int st = blockIdx.x * 64, bh = blockIdx.y;
    const unsigned short* src = V + (long)bh * S_ * PDP;
    unsigned short* dst = Vt + (long)bh * PDP * S_;
#pragma unroll
    for (int i = 0; i < 2; i++) {
        int c = tid + i * 256;
        int row = c >> 3, seg = (c & 7) ^ (row & 7);
        async_copy16(&src[(long)(st + row) * PDP + seg * 8], &T[c * 8]);
    }
    __syncthreads();
    const int d = tid >> 2;
    unsigned short tmp[16];
#pragma unroll
    for (int j = 0; j < 16; j++) {
        int sl = (tid & 3) * 16 + j;
        unsigned short v = T[sl * 64 + ((d >> 3) ^ (sl & 7)) * 8 + (d & 7)];
        tmp[j] = (d < PD_) ? v : ((d == PD_) ? (unsigned short)0x3F80 : (unsigned short)0);
    }
    *(uint4*)&dst[(long)d * S_ + st + (tid & 3) * 16] = *(uint4*)&tmp[0];
    *(uint4*)&dst[(long)d * S_ + st + (tid & 3) * 16 + 8] = *(uint4*)&tmp[8];
}

// --------------------------------------------------------- output projection
__global__ __launch_bounds__(256) void gemm_out_kernel(
    const unsigned short* __restrict__ Ctx, const unsigned short* __restrict__ Wot,
    const float* __restrict__ bo, float* __restrict__ Out) {
    __shared__ __align__(16) unsigned short Asm[128 * 64];
    __shared__ __align__(16) unsigned short Bsm[128 * 64];
    const int m0 = blockIdx.x * 128, n0 = blockIdx.y * 128;
    floatx4 acc[4][4];
    gemm_core(Ctx + (long)m0 * D_, Wot + (long)n0 * D_, Asm, Bsm, acc);

    const int tid = threadIdx.x, lane = tid & 63, w = tid >> 6;
    const int wr = (w >> 1) * 64, wc = (w & 1) * 64;
    const int l15 = lane & 15, l4 = lane >> 4;
#pragma unroll
    for (int nt = 0; nt < 4; nt++) {
        int n = n0 + wc + nt * 16 + l15;
        float bb = bo[n];
#pragma unroll
        for (int mt = 0; mt < 4; mt++) {
#pragma unroll
            for (int r = 0; r < 4; r++) {
                int m = m0 + wr + mt * 16 + l4 * 4 + r;
                Out[(long)m * D_ + n] = acc[mt][nt][r] + bb;
            }
        }
    }
}

// ------------------------------------------------------------ flash attention
// One block = (b,h) x 256-query tile; 4 waves x 64 queries (4 groups of 16).
// Grid: x = bh (128), y = qt (4) => all qt-blocks of a bh share an XCD L2.
// S^T = K*Q^T; fixed-max softmax P = exp2 (scale*log2e folded into Q).
// Q pad (d>=48) zeroed IN-REGISTER (so no buffer memset; K pad garbage is
// multiplied by zero). l via ones-column at V^T row d=48.
__global__ __launch_bounds__(256) void attn_kernel(
    const unsigned short* __restrict__ Qg, const unsigned short* __restrict__ Kg,
    const unsigned short* __restrict__ Vtg, unsigned short* __restrict__ Ctx) {
    __shared__ __align__(16) unsigned short Ks[64 * 64];    // [key][d] swizzled
    __shared__ __align__(16) unsigned short Vs[64 * 64];    // [d][key] swizzled
    __shared__ __align__(16) unsigned short Ps[4][64 * 64]; // per-wave [q][key] swizzled
    const int tid = threadIdx.x, lane = tid & 63, w = tid >> 6;
    const int l15 = lane & 15, l4 = lane >> 4;
    const int bh = blockIdx.x, qt = blockIdx.y;
    const long qkbase = (long)bh * S_ * PDP;   // Q/K: [bh][s][64]
    const long vbase  = (long)bh * PDP * S_;   // Vt:  [bh][d][1024]

    // Q B-fragments from global; wave w owns queries w*64..w*64+63
    short8 bq[4][2];
#pragma unroll
    for (int g = 0; g < 4; g++) {
        int qrow = qt * 256 + w * 64 + g * 16 + l15;
        bq[g][0] = *(const short8*)&Qg[qkbase + (long)qrow * PDP + l4 * 8];
        bq[g][1] = *(const short8*)&Qg[qkbase + (long)qrow * PDP + 32 + l4 * 8];
    }
    if (l4 >= 2) {   // zero Q pad d=48..63 (chunk1 lanes l4=2,3 hold k=48..63)
        const short8 z8 = {0, 0, 0, 0, 0, 0, 0, 0};
#pragma unroll
        for (int g = 0; g < 4; g++) bq[g][1] = z8;
    }

    const floatx4 zero = {0.f, 0.f, 0.f, 0.f};
    floatx4 accO[4][4];
#pragma unroll
    for (int g = 0; g < 4; g++)
#pragma unroll
        for (int nt = 0; nt < 4; nt++) accO[g][nt] = zero;

    unsigned short* Pw = &Ps[w][0];

    for (int kt = 0; kt < 16; kt++) {
        __syncthreads();
        // stage K [key][d] and V^T [d][key] tiles: 8KB each, direct-to-LDS
#pragma unroll
        for (int i = 0; i < 2; i++) {
            int c = tid + i * 256;
            int row = c >> 3, seg = (c & 7) ^ (row & 7);
            async_copy16(&Kg[qkbase + (long)(kt * 64 + row) * PDP + seg * 8], &Ks[c * 8]);
            async_copy16(&Vtg[vbase + (long)row * S_ + kt * 64 + seg * 8], &Vs[c * 8]);
        }
        __syncthreads();

        // K A-frags, shared across all 4 query groups
        short8 ak[4][2];
#pragma unroll
        for (int ks = 0; ks < 4; ks++) {
            int kr = ks * 16 + l15;
            ak[ks][0] = *(const short8*)&Ks[kr * 64 + ((l4 ^ (kr & 7)) * 8)];
            ak[ks][1] = *(const short8*)&Ks[kr * 64 + (((4 + l4) ^ (kr & 7)) * 8)];
        }

        // scores + P for all groups
#pragma unroll
        for (int g = 0; g < 4; g++) {
            floatx4 sc[4];
#pragma unroll
            for (int ks = 0; ks < 4; ks++) {
                floatx4 a = zero;
                a = __builtin_amdgcn_mfma_f32_16x16x32_bf16(ak[ks][0], bq[g][0], a, 0, 0, 0);
                a = __builtin_amdgcn_mfma_f32_16x16x32_bf16(ak[ks][1], bq[g][1], a, 0, 0, 0);
                sc[ks] = a;
            }
            int prow = g * 16 + l15;
#pragma unroll
            for (int ks = 0; ks < 4; ks++) {
                unsigned short p4[4];
#pragma unroll
                for (int r = 0; r < 4; r++) p4[r] = f2bf(__builtin_amdgcn_exp2f(sc[ks][r]));
                int addr = prow * 64 + (((ks * 2 + (l4 >> 1)) ^ (prow & 7)) * 8) + (l4 & 1) * 4;
                *(uint2*)&Pw[addr] = *(uint2*)&p4[0];
            }
        }

        // PV: V B-frags hoisted per kk, shared across groups
#pragma unroll
        for (int kk = 0; kk < 2; kk++) {
            short8 bv[4];
#pragma unroll
            for (int nt = 0; nt < 4; nt++) {
                int vr = nt * 16 + l15;
                bv[nt] = *(const short8*)&Vs[vr * 64 + (((kk * 4 + l4) ^ (vr & 7)) * 8)];
            }
#pragma unroll
            for (int g = 0; g < 4; g++) {
                int prow = g * 16 + l15;
                short8 ap = *(const short8*)&Pw[prow * 64 + (((kk * 4 + l4) ^ (prow & 7)) * 8)];
#pragma unroll
                for (int nt = 0; nt < 4; nt++)
                    accO[g][nt] = __builtin_amdgcn_mfma_f32_16x16x32_bf16(ap, bv[nt], accO[g][nt], 0, 0, 0);
            }
        }
    }

    // epilogue: l = accO[g][3] at l15==0 (d=48 ones-column); out = accO/l
    const int b = bh >> 4, h = bh & 15;
#pragma unroll
    for (int g = 0; g < 4; g++) {
#pragma unroll
        for (int r = 0; r < 4; r++) {
            float lsum = __shfl(accO[g][3][r], lane & 48);
            float inv = 1.0f / lsum;
            int q = qt * 256 + w * 64 + g * 16 + l4 * 4 + r;
            long rowoff = (long)(b * S_ + q) * D_ + h * PD_;
#pragma unroll
            for (int nt = 0; nt < 3; nt++)
                Ctx[rowoff + nt * 16 + l15] = f2bf(accO[g][nt][r] * inv);
        }
    }
}

// ---------------------------------------------------------------------------
extern "C" void kernel_launch(void* const* d_in, const int* in_sizes, int n_in,
                              void* d_out, int out_size, void* d_ws, size_t ws_size,
                              hipStream_t stream) {
    const float* X  = (const float*)d_in[0];
    const float* Wq = (const float*)d_in[1];
    const float* bq = (const float*)d_in[2];
    const float* Wk = (const float*)d_in[3];
    const float* bk = (const float*)d_in[4];
    const float* Wv = (const float*)d_in[5];
    const float* bv = (const float*)d_in[6];
    const float* Wo = (const float*)d_in[7];
    const float* bo = (const float*)d_in[8];

    unsigned char* ws = (unsigned char*)d_ws;
    const long XB_BYTES  = (long)M_ * D_ * 2;         // 12,582,912
    const long WT_BYTES  = (long)D_ * D_ * 2;         // 1,179,648
    const long QKV_BYTES = (long)BH_ * S_ * PDP * 2;  // 16,777,216

    unsigned short* Xbf   = (unsigned short*)(ws);
    unsigned short* Wtall = (unsigned short*)(ws + XB_BYTES);
    unsigned short* Qws   = (unsigned short*)(ws + XB_BYTES + 4 * WT_BYTES);
    unsigned short* Kws   = Qws + QKV_BYTES / 2;
    unsigned short* Vws   = Kws + QKV_BYTES / 2;
    unsigned short* Vtws  = Vws + QKV_BYTES / 2;
    unsigned short* Ctx   = Vws;  // aliases V (dead after transpose_v)

    prep_kernel<<<8448, 256, 0, stream>>>(X, Xbf, Wq, Wk, Wv, Wo, Wtall);
    gemm_qkv_kernel<<<dim3(64, 6, 3), 256, 0, stream>>>(Xbf, Wtall, bq, bk, bv, Qws);
    transpose_v_kernel<<<dim3(16, 128), 256, 0, stream>>>(Vws, Vtws);
    attn_kernel<<<dim3(128, 4), 256, 0, stream>>>(Qws, Kws, Vtws, Ctx);
    gemm_out_kernel<<<dim3(64, 6), 256, 0, stream>>>(
        Ctx, Wtall + 3 * (WT_BYTES / 2), bo, (float*)d_out);
}